// Round 6
// baseline (381.489 us; speedup 1.0000x reference)
//
#include <hip/hip_runtime.h>
#include <hip/hip_bf16.h>

#define N_NODES 100000
#define N_EDGES 3200000
#define NBKT 391      // ceil(N_NODES/256): bucket = dst>>8
#define BKT_CAP 10240 // avg 8184 edges/bucket, +23 sigma margin
#define NOCT (N_NODES / 8)

typedef __hip_bfloat16 bf16;
typedef unsigned int uint;
typedef __attribute__((ext_vector_type(8))) short bf16x8;
typedef __attribute__((ext_vector_type(4))) float f32x4;

__device__ __forceinline__ float b2f(bf16 v) { return __bfloat162float(v); }

__device__ __forceinline__ float bits2f(unsigned short w) {
    union { unsigned short u; bf16 b; } c;
    c.u = w;
    return __bfloat162float(c.b);
}
__device__ __forceinline__ unsigned short f2bits(float f) {  // truncate
    return (unsigned short)(__float_as_uint(f) >> 16);
}
__device__ __forceinline__ unsigned short f2bf_bits(float f) {  // RNE
    bf16 b = __float2bfloat16(f);
    unsigned short u;
    __builtin_memcpy(&u, &b, 2);
    return u;
}
__device__ __forceinline__ float lo16f(uint w) { return __uint_as_float(w << 16); }
__device__ __forceinline__ float hi16f(uint w) { return __uint_as_float(w & 0xffff0000u); }

// runtime dtype accessors -------------------------------------------------
__device__ __forceinline__ int get_idx(const void* ei, long long pos, int is64) {
    if (is64) return (int)((const long long*)ei)[pos];
    return ((const int*)ei)[pos];
}
__device__ __forceinline__ float get_f(const void* p, long long pos, int isbf) {
    if (isbf) return b2f(((const bf16*)p)[pos]);
    return ((const float*)p)[pos];
}

// ---------------- dtype detection (1 wave) ----------------
__global__ void detect_kernel(const void* __restrict__ x,
                              const void* __restrict__ ei,
                              int* __restrict__ flags) {
    int lane = threadIdx.x;  // 64 threads
    const unsigned short* xw = (const unsigned short*)x;
    float v = bits2f(xw[2 * lane]);
    bool plaus = (v == v) && fabsf(v) > 1e-3f && fabsf(v) < 1e2f;
    unsigned long long m1 = __ballot(plaus);
    const int* iw = (const int*)ei;
    bool z = (iw[2 * lane + 1] == 0);
    unsigned long long m2 = __ballot(z);
    if (lane == 0) {
        flags[0] = (__popcll(m1) >= 32) ? 1 : 0;
        flags[1] = (__popcll(m2) == 64) ? 1 : 0;
    }
}

// ---------------- transpose x -> slice-major xT[4][N][16] (bf16 only) -----
// Each 16-ch slice = 3.2 MB CONTIGUOUS (per-XCD-L2-resident; full-line use).
__global__ __launch_bounds__(256) void transpose_kernel(
    const void* __restrict__ x, uint4* __restrict__ xt,
    const int* __restrict__ flags) {
    if (!flags[0]) return;  // fp32 path uses original layout
    int i = blockIdx.x * 256 + threadIdx.x;  // N*4 chunks of 32B
    if (i >= N_NODES * 4) return;
    int node = i >> 2, cz = i & 3;
    const uint4* x4 = (const uint4*)x;
    uint4 a = x4[(long long)node * 8 + cz * 2];
    uint4 b = x4[(long long)node * 8 + cz * 2 + 1];
    long long o = (long long)cz * (N_NODES * 2) + (long long)node * 2;
    xt[o] = a;
    xt[o + 1] = b;
}

// ---------------- pass A: bucket edges by dst>>8 ----------------
__global__ __launch_bounds__(256) void scatterA_kernel(
    const void* __restrict__ ei, int* __restrict__ bucket_cursor,
    uint* __restrict__ bucket_data, const int* __restrict__ flags) {
    __shared__ int lhist[NBKT];
    __shared__ int lbase[NBKT];
    int is64 = flags[1];
    int t = threadIdx.x;
    int chunk0 = blockIdx.x * 8192;
    int dreg[32];

    for (int i = t; i < NBKT; i += 256) lhist[i] = 0;
    __syncthreads();
#pragma unroll
    for (int j = 0; j < 32; j++) {
        int e = chunk0 + j * 256 + t;
        int d = -1;
        if (e < N_EDGES) {
            d = get_idx(ei, (long long)N_EDGES + e, is64);
            atomicAdd(&lhist[d >> 8], 1);
        }
        dreg[j] = d;
    }
    __syncthreads();
    for (int i = t; i < NBKT; i += 256) {
        int c = lhist[i];
        lbase[i] = c ? atomicAdd(&bucket_cursor[i], c) : 0;
        lhist[i] = 0;  // reuse as local cursor
    }
    __syncthreads();
#pragma unroll
    for (int j = 0; j < 32; j++) {
        int e = chunk0 + j * 256 + t;
        int d = dreg[j];
        if (d >= 0) {
            int s = get_idx(ei, e, is64);
            int b = d >> 8;
            int o = lbase[b] + atomicAdd(&lhist[b], 1);
            if (o < BKT_CAP)
                bucket_data[(long long)b * BKT_CAP + o] = ((uint)(d & 255) << 17) | (uint)s;
        }
    }
}

// ---------------- scan bucket counts -> bucket base ----------------
__global__ void scanBuckets_kernel(const int* __restrict__ cnt,
                                   int* __restrict__ base) {
    __shared__ int buf[512];
    int t = threadIdx.x;  // 512 threads
    int v = (t < NBKT) ? cnt[t] : 0;
    buf[t] = v;
    __syncthreads();
    for (int off = 1; off < 512; off <<= 1) {
        int add = (t >= off) ? buf[t - off] : 0;
        __syncthreads();
        buf[t] += add;
        __syncthreads();
    }
    if (t < NBKT) base[t] = buf[t] - v;  // exclusive
}

// ---------------- pass B: per-bucket CSR build ----------------
__global__ __launch_bounds__(256) void csrB_kernel(
    const int* __restrict__ bucket_cnt, const int* __restrict__ bucket_base,
    const uint* __restrict__ bucket_data, int* __restrict__ csr_src,
    int* __restrict__ row_start) {
    __shared__ int lh[256];
    __shared__ int buf[256];
    int b = blockIdx.x;
    int t = threadIdx.x;
    int cnt = bucket_cnt[b];
    if (cnt > BKT_CAP) cnt = BKT_CAP;
    int base = bucket_base[b];
    const uint* bd = bucket_data + (long long)b * BKT_CAP;

    lh[t] = 0;
    __syncthreads();
    for (int i = t; i < cnt; i += 256) atomicAdd(&lh[bd[i] >> 17], 1);
    __syncthreads();
    int v = lh[t];
    buf[t] = v;
    __syncthreads();
    for (int off = 1; off < 256; off <<= 1) {
        int add = (t >= off) ? buf[t - off] : 0;
        __syncthreads();
        buf[t] += add;
        __syncthreads();
    }
    int excl = buf[t] - v;
    int g = (b << 8) + t;
    if (g < N_NODES) row_start[g] = base + excl;
    lh[t] = excl;  // reuse as local cursor
    __syncthreads();
    for (int i = t; i < cnt; i += 256) {
        uint e = bd[i];
        int o = atomicAdd(&lh[e >> 17], 1);
        csr_src[base + o] = (int)(e & 0x1FFFFu);
    }
    if (b == 0 && t == 0) row_start[N_NODES] = N_EDGES;
}

#define ACCF4(acc, v, v2)                                                        \
    acc[0] += __uint_as_float((v).x) + __uint_as_float((v2).x);                   \
    acc[1] += __uint_as_float((v).y) + __uint_as_float((v2).y);                   \
    acc[2] += __uint_as_float((v).z) + __uint_as_float((v2).z);                   \
    acc[3] += __uint_as_float((v).w) + __uint_as_float((v2).w);

// ---- shared slice-gather core: 8 nodes/wave, 8 lanes/node, 2ch/lane ------
// slice = [N][16] bf16 viewed as uint[N*8]. In-lane accumulation: NO
// reduction shuffles; one src-broadcast shuffle per edge. csr_src is read
// ONCE per pass -> NON-TEMPORAL load (don't evict the L2-resident slice).
// Slice loads (su) stay cached. 8 loads in flight per lane.
__device__ __forceinline__ void slice_gather8(
    const uint* __restrict__ su, const int* __restrict__ row_start,
    const int* __restrict__ csr_src, int nb0, int g8, int c8, int lane,
    float& a0, float& a1, int& dg_out) {
    // lanes 0..8 load row_start[nb0+l]; groups read their own bounds
    int rl = (lane <= 8) ? row_start[nb0 + lane] : 0;
    int sg = __shfl(rl, g8 >> 3, 64);
    int eg = __shfl(rl, (g8 >> 3) + 1, 64);
    int dg = eg - sg;
    // wave-uniform maxd: groups g^1,g^2,g^4 live at lane^8,^16,^32
    int maxd = dg;
    maxd = max(maxd, __shfl_xor(maxd, 8, 64));
    maxd = max(maxd, __shfl_xor(maxd, 16, 64));
    maxd = max(maxd, __shfl_xor(maxd, 32, 64));

    float s0f = 0.0f, s1f = 0.0f;
    for (int base = 0; base < maxd; base += 8) {
        int pf = sg + base + c8;
        int sreg = (pf < eg) ? __builtin_nontemporal_load(csr_src + pf) : 0;
        int ss[8];
#pragma unroll
        for (int u = 0; u < 8; u++) ss[u] = __shfl(sreg, g8 + u, 64);
        uint wv[8];
#pragma unroll
        for (int u = 0; u < 8; u++)
            wv[u] = (base + u < dg) ? su[(ss[u] << 3) + c8] : 0u;
#pragma unroll
        for (int u = 0; u < 8; u++) {
            s0f += lo16f(wv[u]);
            s1f += hi16f(wv[u]);
        }
    }
    a0 = s0f;
    a1 = s1f;
    dg_out = dg;
}

// ---------------- layer-1 gather (bf16: slice-major xT) -------------------
// TWO LAUNCHES of 2 slices each, replicating r2-node2's empirically PROVEN
// residency configuration exactly: cz = cz_base + ((bid&7)>>2) (bit2 of bid
// selects between the 2 concurrent slices -> one slice per XCD under the
// granularity-4 bid->XCD round-robin), node-strided loop, slice-major
// contiguous 3.2 MB buffer. r2-node2 measured FETCH=38MB = csr+compulsory,
// i.e. ~100% L2 hit on gathers, with this exact mapping.
__global__ __launch_bounds__(256) void gather1_kernel(
    const void* __restrict__ x, const uint* __restrict__ xtu,
    const int* __restrict__ row_start, const int* __restrict__ csr_src,
    bf16* __restrict__ aggbuf, const int* __restrict__ flags, int cz_base) {
    int isbf = flags[0];
    int t = threadIdx.x;
    int lane = t & 63;
    int w = t >> 6;
    int bid = blockIdx.x;

    if (isbf) {
        int cz = cz_base + ((bid & 7) >> 2);                   // 2 slices/launch
        int wid = ((((bid >> 3) << 2) | (bid & 3)) << 2) + w;  // wave id within cz
        int nw = gridDim.x * 2;                                // waves per cz
        int g8 = lane & 0x38, c8 = lane & 7;
        int g = lane >> 3;
        const uint* su = xtu + (long long)cz * (N_NODES * 8);
        uint* ag = (uint*)aggbuf;
        for (int oct = wid; oct < NOCT; oct += nw) {
            int nb0 = oct * 8;
            float a0, a1;
            int dg;
            slice_gather8(su, row_start, csr_src, nb0, g8, c8, lane, a0, a1, dg);
            float inv = 1.0f / fmaxf((float)dg, 1.0f);
            uint pk = (uint)f2bf_bits(a0 * inv) |
                      ((uint)f2bf_bits(a1 * inv) << 16);
            __builtin_nontemporal_store(pk, ag + (nb0 + g) * 32 + cz * 8 + c8);
        }
    } else {
        if (cz_base != 0) return;  // fp32 path does all work in launch 0
        // fp32 fallback: full-row gather over original x (round-0 code)
        int gw = (bid * 256 + t) >> 6;
        int nwv = (gridDim.x * 256) >> 6;
        int e4 = lane >> 4, q16 = lane & 15;
        const uint4* xf = (const uint4*)x;  // fp32 row = 16 uint4
        for (int p = gw; p * 2 < N_NODES; p += nwv) {
            int na = p * 2, nb = p * 2 + 1;
            int sa = row_start[na], ea = row_start[na + 1];
            int sb = row_start[nb], eb = row_start[nb + 1];
            int da = ea - sa, db = eb - sb;
            int maxd = max(da, db);
            float accA[4] = {0, 0, 0, 0};
            float accB[4] = {0, 0, 0, 0};
            for (int off = 0; off < maxd; off += 16) {
                int iA0 = sa + off + e4, iA1 = iA0 + 4, iA2 = iA0 + 8, iA3 = iA0 + 12;
                int iB0 = sb + off + e4, iB1 = iB0 + 4, iB2 = iB0 + 8, iB3 = iB0 + 12;
                int sA0 = (iA0 < ea) ? csr_src[iA0] : -1;
                int sA1 = (iA1 < ea) ? csr_src[iA1] : -1;
                int sA2 = (iA2 < ea) ? csr_src[iA2] : -1;
                int sA3 = (iA3 < ea) ? csr_src[iA3] : -1;
                int sB0 = (iB0 < eb) ? csr_src[iB0] : -1;
                int sB1 = (iB1 < eb) ? csr_src[iB1] : -1;
                int sB2 = (iB2 < eb) ? csr_src[iB2] : -1;
                int sB3 = (iB3 < eb) ? csr_src[iB3] : -1;
                uint4 vA0 = {0,0,0,0}, vA1 = {0,0,0,0}, vA2 = {0,0,0,0}, vA3 = {0,0,0,0};
                uint4 vB0 = {0,0,0,0}, vB1 = {0,0,0,0}, vB2 = {0,0,0,0}, vB3 = {0,0,0,0};
                if (sA0 >= 0) vA0 = xf[sA0 * 16 + q16];
                if (sA1 >= 0) vA1 = xf[sA1 * 16 + q16];
                if (sA2 >= 0) vA2 = xf[sA2 * 16 + q16];
                if (sA3 >= 0) vA3 = xf[sA3 * 16 + q16];
                if (sB0 >= 0) vB0 = xf[sB0 * 16 + q16];
                if (sB1 >= 0) vB1 = xf[sB1 * 16 + q16];
                if (sB2 >= 0) vB2 = xf[sB2 * 16 + q16];
                if (sB3 >= 0) vB3 = xf[sB3 * 16 + q16];
                ACCF4(accA, vA0, vA1)
                ACCF4(accA, vA2, vA3)
                ACCF4(accB, vB0, vB1)
                ACCF4(accB, vB2, vB3)
            }
#pragma unroll
            for (int m = 16; m <= 32; m <<= 1)
#pragma unroll
                for (int k = 0; k < 4; k++) {
                    accA[k] += __shfl_xor(accA[k], m, 64);
                    accB[k] += __shfl_xor(accB[k], m, 64);
                }
            float avA = 0.0f, avB = 0.0f;
#pragma unroll
            for (int k = 0; k < 4; k++) {
                float vA = __shfl(accA[k], lane >> 2, 64);
                float vB = __shfl(accB[k], lane >> 2, 64);
                avA = ((lane & 3) == k) ? vA : avA;
                avB = ((lane & 3) == k) ? vB : avB;
            }
            avA *= 1.0f / fmaxf((float)da, 1.0f);
            avB *= 1.0f / fmaxf((float)db, 1.0f);
            aggbuf[(long long)na * 64 + lane] = __float2bfloat16(avA);
            aggbuf[(long long)nb * 64 + lane] = __float2bfloat16(avB);
        }
    }
}

// ---------------- layer-1+2 GEMMs (MFMA, dense coalesced staging) ----------------
// Writes z/r slice-major: zbufT[2][N][16], rbufT[2][N][16] (for node2's L2 slicing).
__global__ __launch_bounds__(256) void gemm1_kernel(
    const void* __restrict__ x, const bf16* __restrict__ aggbuf,
    const void* __restrict__ W1l, const void* __restrict__ b1l,
    const void* __restrict__ W1r, const void* __restrict__ W2l,
    const void* __restrict__ b2l, const void* __restrict__ W2r,
    bf16* __restrict__ zbufT, bf16* __restrict__ rbufT,
    const int* __restrict__ flags) {
    __shared__ __align__(16) unsigned short sW1t[64][136];
    __shared__ __align__(16) unsigned short sA[64][136];
    __shared__ __align__(16) unsigned short sW2t[64][72];
    __shared__ __align__(16) unsigned short sH[64][72];
    __shared__ float sB1[64];
    __shared__ float sB2[32];

    int isbf = flags[0];
    int t = threadIdx.x;
    int n0 = blockIdx.x * 64;

    for (int i = t; i < 64 * 128; i += 256) {
        int n = i & 63, k = i >> 6;
        unsigned short v;
        if (isbf)
            v = (k < 64) ? ((const unsigned short*)W1l)[k * 64 + n]
                         : ((const unsigned short*)W1r)[(k - 64) * 64 + n];
        else
            v = f2bits((k < 64) ? ((const float*)W1l)[k * 64 + n]
                                : ((const float*)W1r)[(k - 64) * 64 + n]);
        sW1t[n][k] = v;
    }
    for (int i = t; i < 64 * 64; i += 256) {
        int n = i & 63, k = i >> 6;
        unsigned short v;
        if (isbf)
            v = (n < 32) ? ((const unsigned short*)W2l)[k * 32 + n]
                         : ((const unsigned short*)W2r)[k * 32 + (n - 32)];
        else
            v = f2bits((n < 32) ? ((const float*)W2l)[k * 32 + n]
                                : ((const float*)W2r)[k * 32 + (n - 32)]);
        sW2t[n][k] = v;
    }
    if (t < 64) sB1[t] = get_f(b1l, t, isbf);
    if (t < 32) sB2[t] = get_f(b2l, t, isbf);

    const uint4* ag4 = (const uint4*)aggbuf;
    if (isbf) {
        const uint4* x4 = (const uint4*)x;
        for (int i = t; i < 64 * 16; i += 256) {
            int m = i >> 4, c = i & 15;
            int nn = min(n0 + m, N_NODES - 1);
            uint4 v = (c < 8) ? ag4[(long long)nn * 8 + c]
                              : x4[(long long)nn * 8 + (c - 8)];
            *(uint4*)&sA[m][c * 8] = v;
        }
    } else {
        for (int i = t; i < 64 * 8; i += 256) {
            int m = i >> 3, c = i & 7;
            int nn = min(n0 + m, N_NODES - 1);
            *(uint4*)&sA[m][c * 8] = ag4[(long long)nn * 8 + c];
        }
        const float* xf = (const float*)x;
        for (int i = t; i < 64 * 64; i += 256) {
            int m = i >> 6, c = i & 63;
            int nn = min(n0 + m, N_NODES - 1);
            sA[m][64 + c] = f2bf_bits(xf[(long long)nn * 64 + c]);
        }
    }
    __syncthreads();

    int w = t >> 6, lane = t & 63;
    int mbase = w * 16;
    int q = lane >> 4, r15 = lane & 15;
    f32x4 acc1[4] = {{0,0,0,0},{0,0,0,0},{0,0,0,0},{0,0,0,0}};
#pragma unroll
    for (int ks = 0; ks < 4; ks++) {
        bf16x8 afrag = *(const bf16x8*)&sA[mbase + r15][ks * 32 + q * 8];
#pragma unroll
        for (int nt = 0; nt < 4; nt++) {
            bf16x8 bfrag = *(const bf16x8*)&sW1t[nt * 16 + r15][ks * 32 + q * 8];
            acc1[nt] = __builtin_amdgcn_mfma_f32_16x16x32_bf16(afrag, bfrag, acc1[nt], 0, 0, 0);
        }
    }
#pragma unroll
    for (int nt = 0; nt < 4; nt++) {
        int col = nt * 16 + r15;
        float bias = sB1[col];
#pragma unroll
        for (int rr = 0; rr < 4; rr++) {
            int m = mbase + q * 4 + rr;
            sH[m][col] = f2bf_bits(fmaxf(acc1[nt][rr] + bias, 0.0f));
        }
    }
    __syncthreads();

    f32x4 acc2[4] = {{0,0,0,0},{0,0,0,0},{0,0,0,0},{0,0,0,0}};
#pragma unroll
    for (int ks = 0; ks < 2; ks++) {
        bf16x8 afrag = *(const bf16x8*)&sH[mbase + r15][ks * 32 + q * 8];
#pragma unroll
        for (int nt = 0; nt < 4; nt++) {
            bf16x8 bfrag = *(const bf16x8*)&sW2t[nt * 16 + r15][ks * 32 + q * 8];
            acc2[nt] = __builtin_amdgcn_mfma_f32_16x16x32_bf16(afrag, bfrag, acc2[nt], 0, 0, 0);
        }
    }
#pragma unroll
    for (int nt = 0; nt < 4; nt++) {
        int col = nt * 16 + r15;
#pragma unroll
        for (int rr = 0; rr < 4; rr++) {
            int m = mbase + q * 4 + rr;
            int n = n0 + m;
            if (n < N_NODES) {
                float v = acc2[nt][rr];
                if (col < 32) {
                    zbufT[(long long)(col >> 4) * (N_NODES * 16) +
                          (long long)n * 16 + (col & 15)] = __float2bfloat16(v);
                } else {
                    int c2 = col - 32;
                    rbufT[(long long)(c2 >> 4) * (N_NODES * 16) +
                          (long long)n * 16 + (c2 & 15)] =
                        __float2bfloat16(v + sB2[c2]);
                }
            }
        }
    }
}

// ---------------- layer-2: gather z (slice-major, shuffle-free, nt-streams)
// 2 slices x 16ch; cz=(bid%8)>>2 pins slice (empirically verified r2: 37MB).
__global__ __launch_bounds__(256) void node2_kernel(
    const int* __restrict__ row_start, const int* __restrict__ csr_src,
    const uint* __restrict__ zTu, const bf16* __restrict__ rbufT,
    void* __restrict__ out, const int* __restrict__ flags) {
    int isbf = flags[0];
    int t = threadIdx.x;
    int lane = t & 63;
    int w = t >> 6;
    int bid = blockIdx.x;
    int cz = (bid & 7) >> 2;                                   // slice 0..1
    int wid = ((((bid >> 3) << 2) | (bid & 3)) << 2) + w;      // wave id within cz
    int nw = gridDim.x * 2;                                    // waves per cz
    int g8 = lane & 0x38, c8 = lane & 7;
    int g = lane >> 3;
    const uint* su = zTu + (long long)cz * (N_NODES * 8);
    const uint* ru = (const uint*)(rbufT + (long long)cz * (N_NODES * 16));

    for (int oct = wid; oct < NOCT; oct += nw) {
        int nb0 = oct * 8;
        float a0, a1;
        int dg;
        slice_gather8(su, row_start, csr_src, nb0, g8, c8, lane, a0, a1, dg);
        float inv = 1.0f / fmaxf((float)dg, 1.0f);
        int n = nb0 + g;
        uint rb = __builtin_nontemporal_load(ru + n * 8 + c8);
        float r0 = a0 * inv + lo16f(rb);
        float r1 = a1 * inv + hi16f(rb);
        if (isbf) {
            uint pk = (uint)f2bf_bits(r0) | ((uint)f2bf_bits(r1) << 16);
            __builtin_nontemporal_store(pk, (uint*)out + n * 16 + cz * 8 + c8);
        } else {
            float* of = (float*)out;
            __builtin_nontemporal_store(r0, of + (long long)n * 32 + cz * 16 + 2 * c8);
            __builtin_nontemporal_store(r1, of + (long long)n * 32 + cz * 16 + 2 * c8 + 1);
        }
    }
}

extern "C" void kernel_launch(void* const* d_in, const int* in_sizes, int n_in,
                              void* d_out, int out_size, void* d_ws, size_t ws_size,
                              hipStream_t stream) {
    const void* x = d_in[0];
    const void* ei = d_in[1];  // [2, E]: src = [0,E), dst = [E,2E)
    const void* W1l = d_in[2];
    const void* b1l = d_in[3];
    const void* W1r = d_in[4];
    const void* W2l = d_in[5];
    const void* b2l = d_in[6];
    const void* W2r = d_in[7];

    // workspace layout (~42 MB), triple-aliased across pipeline phases:
    //   [0, 16.0MB)      bucket_data (dead after csrB)  / aggbuf (gather1->gemm1)
    //   [29.2, 42.0MB)   xT (transpose->gather1, bf16)  / zbufT+rbufT (gemm1->node2)
    char* ws = (char*)d_ws;
    uint* bucket_data = (uint*)ws;                    // NBKT*BKT_CAP u32 = 16.0 MB
    bf16* aggbuf = (bf16*)ws;                         // N*64 bf16 = 12.8 MB (alias)
    int* csr_src = (int*)(ws + 16015424);             // E i32 = 12.8 MB
    int* row_start = (int*)(ws + 28815424);           // N+1 i32
    int* bucket_cursor = (int*)(ws + 29215488);       // NBKT i32
    int* bucket_base = (int*)(ws + 29217088);         // NBKT i32
    uint* xtu = (uint*)(ws + 29218688);               // 4*N*16 bf16 = 12.8 MB (alias)
    bf16* zbufT = (bf16*)(ws + 29218688);             // 2*N*16 bf16 = 6.4 MB
    bf16* rbufT = (bf16*)(ws + 35618688);             // 2*N*16 bf16 = 6.4 MB
    int* flags = (int*)(ws + 42018688);               // 2 i32

    hipMemsetAsync(bucket_cursor, 0, NBKT * 4, stream);

    detect_kernel<<<1, 64, 0, stream>>>(x, ei, flags);
    transpose_kernel<<<1563, 256, 0, stream>>>(x, (uint4*)xtu, flags);
    scatterA_kernel<<<NBKT, 256, 0, stream>>>(ei, bucket_cursor, bucket_data, flags);
    scanBuckets_kernel<<<1, 512, 0, stream>>>(bucket_cursor, bucket_base);
    csrB_kernel<<<NBKT, 256, 0, stream>>>(bucket_cursor, bucket_base, bucket_data,
                                          csr_src, row_start);
    gather1_kernel<<<4096, 256, 0, stream>>>(x, xtu, row_start, csr_src, aggbuf,
                                             flags, 0);
    gather1_kernel<<<4096, 256, 0, stream>>>(x, xtu, row_start, csr_src, aggbuf,
                                             flags, 2);
    gemm1_kernel<<<1563, 256, 0, stream>>>(x, aggbuf, W1l, b1l, W1r, W2l, b2l,
                                           W2r, zbufT, rbufT, flags);
    node2_kernel<<<4096, 256, 0, stream>>>(row_start, csr_src, (const uint*)zbufT,
                                           rbufT, d_out, flags);
}

// Round 7
// 379.697 us; speedup vs baseline: 1.0047x; 1.0047x over previous
//
#include <hip/hip_runtime.h>
#include <hip/hip_bf16.h>

#define N_NODES 100000
#define N_EDGES 3200000
#define NBKT 391      // ceil(N_NODES/256): bucket = dst>>8
#define BKT_CAP 10240 // avg 8184 edges/bucket, +23 sigma margin
#define NOCT (N_NODES / 8)

typedef __hip_bfloat16 bf16;
typedef unsigned int uint;
typedef __attribute__((ext_vector_type(8))) short bf16x8;
typedef __attribute__((ext_vector_type(4))) float f32x4;

__device__ __forceinline__ float b2f(bf16 v) { return __bfloat162float(v); }

__device__ __forceinline__ float bits2f(unsigned short w) {
    union { unsigned short u; bf16 b; } c;
    c.u = w;
    return __bfloat162float(c.b);
}
__device__ __forceinline__ unsigned short f2bits(float f) {  // truncate
    return (unsigned short)(__float_as_uint(f) >> 16);
}
__device__ __forceinline__ unsigned short f2bf_bits(float f) {  // RNE
    bf16 b = __float2bfloat16(f);
    unsigned short u;
    __builtin_memcpy(&u, &b, 2);
    return u;
}
__device__ __forceinline__ float lo16f(uint w) { return __uint_as_float(w << 16); }
__device__ __forceinline__ float hi16f(uint w) { return __uint_as_float(w & 0xffff0000u); }

// runtime dtype accessors -------------------------------------------------
__device__ __forceinline__ int get_idx(const void* ei, long long pos, int is64) {
    if (is64) return (int)((const long long*)ei)[pos];
    return ((const int*)ei)[pos];
}
__device__ __forceinline__ float get_f(const void* p, long long pos, int isbf) {
    if (isbf) return b2f(((const bf16*)p)[pos]);
    return ((const float*)p)[pos];
}

// ---------------- dtype detection (1 wave) ----------------
__global__ void detect_kernel(const void* __restrict__ x,
                              const void* __restrict__ ei,
                              int* __restrict__ flags) {
    int lane = threadIdx.x;  // 64 threads
    const unsigned short* xw = (const unsigned short*)x;
    float v = bits2f(xw[2 * lane]);
    bool plaus = (v == v) && fabsf(v) > 1e-3f && fabsf(v) < 1e2f;
    unsigned long long m1 = __ballot(plaus);
    const int* iw = (const int*)ei;
    bool z = (iw[2 * lane + 1] == 0);
    unsigned long long m2 = __ballot(z);
    if (lane == 0) {
        flags[0] = (__popcll(m1) >= 32) ? 1 : 0;
        flags[1] = (__popcll(m2) == 64) ? 1 : 0;
    }
}

// ---------------- transpose x -> slice-major xT, TWO slices per launch ----
// Producer->consumer adjacency: each transpose2 launch writes 6.4 MB of
// slice-major xT IMMEDIATELY before the gather launch that reads it
// (replicating the gemm1->node2 adjacency where residency was proven).
__global__ __launch_bounds__(256) void transpose2_kernel(
    const void* __restrict__ x, uint4* __restrict__ xt,
    const int* __restrict__ flags, int cz_base) {
    if (!flags[0]) return;  // fp32 path uses original layout
    int i = blockIdx.x * 256 + threadIdx.x;  // [0, N*2): (node, slice-pair)
    if (i >= N_NODES * 2) return;
    int node = i >> 1, cz = cz_base + (i & 1);
    const uint4* x4 = (const uint4*)x;
    uint4 a = x4[(long long)node * 8 + cz * 2];
    uint4 b = x4[(long long)node * 8 + cz * 2 + 1];
    long long o = (long long)cz * (N_NODES * 2) + (long long)node * 2;
    xt[o] = a;
    xt[o + 1] = b;
}

// ---------------- pass A: bucket edges by dst>>8 ----------------
__global__ __launch_bounds__(256) void scatterA_kernel(
    const void* __restrict__ ei, int* __restrict__ bucket_cursor,
    uint* __restrict__ bucket_data, const int* __restrict__ flags) {
    __shared__ int lhist[NBKT];
    __shared__ int lbase[NBKT];
    int is64 = flags[1];
    int t = threadIdx.x;
    int chunk0 = blockIdx.x * 8192;
    int dreg[32];

    for (int i = t; i < NBKT; i += 256) lhist[i] = 0;
    __syncthreads();
#pragma unroll
    for (int j = 0; j < 32; j++) {
        int e = chunk0 + j * 256 + t;
        int d = -1;
        if (e < N_EDGES) {
            d = get_idx(ei, (long long)N_EDGES + e, is64);
            atomicAdd(&lhist[d >> 8], 1);
        }
        dreg[j] = d;
    }
    __syncthreads();
    for (int i = t; i < NBKT; i += 256) {
        int c = lhist[i];
        lbase[i] = c ? atomicAdd(&bucket_cursor[i], c) : 0;
        lhist[i] = 0;  // reuse as local cursor
    }
    __syncthreads();
#pragma unroll
    for (int j = 0; j < 32; j++) {
        int e = chunk0 + j * 256 + t;
        int d = dreg[j];
        if (d >= 0) {
            int s = get_idx(ei, e, is64);
            int b = d >> 8;
            int o = lbase[b] + atomicAdd(&lhist[b], 1);
            if (o < BKT_CAP)
                bucket_data[(long long)b * BKT_CAP + o] = ((uint)(d & 255) << 17) | (uint)s;
        }
    }
}

// ---------------- scan bucket counts -> bucket base ----------------
__global__ void scanBuckets_kernel(const int* __restrict__ cnt,
                                   int* __restrict__ base) {
    __shared__ int buf[512];
    int t = threadIdx.x;  // 512 threads
    int v = (t < NBKT) ? cnt[t] : 0;
    buf[t] = v;
    __syncthreads();
    for (int off = 1; off < 512; off <<= 1) {
        int add = (t >= off) ? buf[t - off] : 0;
        __syncthreads();
        buf[t] += add;
        __syncthreads();
    }
    if (t < NBKT) base[t] = buf[t] - v;  // exclusive
}

// ---------------- pass B: per-bucket CSR build ----------------
__global__ __launch_bounds__(256) void csrB_kernel(
    const int* __restrict__ bucket_cnt, const int* __restrict__ bucket_base,
    const uint* __restrict__ bucket_data, int* __restrict__ csr_src,
    int* __restrict__ row_start) {
    __shared__ int lh[256];
    __shared__ int buf[256];
    int b = blockIdx.x;
    int t = threadIdx.x;
    int cnt = bucket_cnt[b];
    if (cnt > BKT_CAP) cnt = BKT_CAP;
    int base = bucket_base[b];
    const uint* bd = bucket_data + (long long)b * BKT_CAP;

    lh[t] = 0;
    __syncthreads();
    for (int i = t; i < cnt; i += 256) atomicAdd(&lh[bd[i] >> 17], 1);
    __syncthreads();
    int v = lh[t];
    buf[t] = v;
    __syncthreads();
    for (int off = 1; off < 256; off <<= 1) {
        int add = (t >= off) ? buf[t - off] : 0;
        __syncthreads();
        buf[t] += add;
        __syncthreads();
    }
    int excl = buf[t] - v;
    int g = (b << 8) + t;
    if (g < N_NODES) row_start[g] = base + excl;
    lh[t] = excl;  // reuse as local cursor
    __syncthreads();
    for (int i = t; i < cnt; i += 256) {
        uint e = bd[i];
        int o = atomicAdd(&lh[e >> 17], 1);
        csr_src[base + o] = (int)(e & 0x1FFFFu);
    }
    if (b == 0 && t == 0) row_start[N_NODES] = N_EDGES;
}

#define ACCF4(acc, v, v2)                                                        \
    acc[0] += __uint_as_float((v).x) + __uint_as_float((v2).x);                   \
    acc[1] += __uint_as_float((v).y) + __uint_as_float((v2).y);                   \
    acc[2] += __uint_as_float((v).z) + __uint_as_float((v2).z);                   \
    acc[3] += __uint_as_float((v).w) + __uint_as_float((v2).w);

// ---- shared slice-gather core: 8 nodes/wave, 8 lanes/node, 2ch/lane ------
// slice = [N][16] bf16 viewed as uint[N*8]. In-lane accumulation: NO
// reduction shuffles; one src-broadcast shuffle per edge. csr_src is read
// ONCE per pass -> NON-TEMPORAL load. Slice loads (su) stay cached.
__device__ __forceinline__ void slice_gather8(
    const uint* __restrict__ su, const int* __restrict__ row_start,
    const int* __restrict__ csr_src, int nb0, int g8, int c8, int lane,
    float& a0, float& a1, int& dg_out) {
    // lanes 0..8 load row_start[nb0+l]; groups read their own bounds
    int rl = (lane <= 8) ? row_start[nb0 + lane] : 0;
    int sg = __shfl(rl, g8 >> 3, 64);
    int eg = __shfl(rl, (g8 >> 3) + 1, 64);
    int dg = eg - sg;
    // wave-uniform maxd: groups g^1,g^2,g^4 live at lane^8,^16,^32
    int maxd = dg;
    maxd = max(maxd, __shfl_xor(maxd, 8, 64));
    maxd = max(maxd, __shfl_xor(maxd, 16, 64));
    maxd = max(maxd, __shfl_xor(maxd, 32, 64));

    float s0f = 0.0f, s1f = 0.0f;
    for (int base = 0; base < maxd; base += 8) {
        int pf = sg + base + c8;
        int sreg = (pf < eg) ? __builtin_nontemporal_load(csr_src + pf) : 0;
        int ss[8];
#pragma unroll
        for (int u = 0; u < 8; u++) ss[u] = __shfl(sreg, g8 + u, 64);
        uint wv[8];
#pragma unroll
        for (int u = 0; u < 8; u++)
            wv[u] = (base + u < dg) ? su[(ss[u] << 3) + c8] : 0u;
#pragma unroll
        for (int u = 0; u < 8; u++) {
            s0f += lo16f(wv[u]);
            s1f += hi16f(wv[u]);
        }
    }
    a0 = s0f;
    a1 = s1f;
    dg_out = dg;
}

// ---------------- layer-1 gather (bf16: slice-major xT) -------------------
// Two launches of 2 slices each; each launch's xT slices were written by a
// transpose2 launch IMMEDIATELY before it (producer-warm, the one
// configuration where gather residency has been measured to work).
__global__ __launch_bounds__(256) void gather1_kernel(
    const void* __restrict__ x, const uint* __restrict__ xtu,
    const int* __restrict__ row_start, const int* __restrict__ csr_src,
    bf16* __restrict__ aggbuf, const int* __restrict__ flags, int cz_base) {
    int isbf = flags[0];
    int t = threadIdx.x;
    int lane = t & 63;
    int w = t >> 6;
    int bid = blockIdx.x;

    if (isbf) {
        int cz = cz_base + ((bid & 7) >> 2);                   // 2 slices/launch
        int wid = ((((bid >> 3) << 2) | (bid & 3)) << 2) + w;  // wave id within cz
        int nw = gridDim.x * 2;                                // waves per cz
        int g8 = lane & 0x38, c8 = lane & 7;
        int g = lane >> 3;
        const uint* su = xtu + (long long)cz * (N_NODES * 8);
        uint* ag = (uint*)aggbuf;
        for (int oct = wid; oct < NOCT; oct += nw) {
            int nb0 = oct * 8;
            float a0, a1;
            int dg;
            slice_gather8(su, row_start, csr_src, nb0, g8, c8, lane, a0, a1, dg);
            float inv = 1.0f / fmaxf((float)dg, 1.0f);
            uint pk = (uint)f2bf_bits(a0 * inv) |
                      ((uint)f2bf_bits(a1 * inv) << 16);
            __builtin_nontemporal_store(pk, ag + (nb0 + g) * 32 + cz * 8 + c8);
        }
    } else {
        if (cz_base != 0) return;  // fp32 path does all work in launch 0
        // fp32 fallback: full-row gather over original x (round-0 code)
        int gw = (bid * 256 + t) >> 6;
        int nwv = (gridDim.x * 256) >> 6;
        int e4 = lane >> 4, q16 = lane & 15;
        const uint4* xf = (const uint4*)x;  // fp32 row = 16 uint4
        for (int p = gw; p * 2 < N_NODES; p += nwv) {
            int na = p * 2, nb = p * 2 + 1;
            int sa = row_start[na], ea = row_start[na + 1];
            int sb = row_start[nb], eb = row_start[nb + 1];
            int da = ea - sa, db = eb - sb;
            int maxd = max(da, db);
            float accA[4] = {0, 0, 0, 0};
            float accB[4] = {0, 0, 0, 0};
            for (int off = 0; off < maxd; off += 16) {
                int iA0 = sa + off + e4, iA1 = iA0 + 4, iA2 = iA0 + 8, iA3 = iA0 + 12;
                int iB0 = sb + off + e4, iB1 = iB0 + 4, iB2 = iB0 + 8, iB3 = iB0 + 12;
                int sA0 = (iA0 < ea) ? csr_src[iA0] : -1;
                int sA1 = (iA1 < ea) ? csr_src[iA1] : -1;
                int sA2 = (iA2 < ea) ? csr_src[iA2] : -1;
                int sA3 = (iA3 < ea) ? csr_src[iA3] : -1;
                int sB0 = (iB0 < eb) ? csr_src[iB0] : -1;
                int sB1 = (iB1 < eb) ? csr_src[iB1] : -1;
                int sB2 = (iB2 < eb) ? csr_src[iB2] : -1;
                int sB3 = (iB3 < eb) ? csr_src[iB3] : -1;
                uint4 vA0 = {0,0,0,0}, vA1 = {0,0,0,0}, vA2 = {0,0,0,0}, vA3 = {0,0,0,0};
                uint4 vB0 = {0,0,0,0}, vB1 = {0,0,0,0}, vB2 = {0,0,0,0}, vB3 = {0,0,0,0};
                if (sA0 >= 0) vA0 = xf[sA0 * 16 + q16];
                if (sA1 >= 0) vA1 = xf[sA1 * 16 + q16];
                if (sA2 >= 0) vA2 = xf[sA2 * 16 + q16];
                if (sA3 >= 0) vA3 = xf[sA3 * 16 + q16];
                if (sB0 >= 0) vB0 = xf[sB0 * 16 + q16];
                if (sB1 >= 0) vB1 = xf[sB1 * 16 + q16];
                if (sB2 >= 0) vB2 = xf[sB2 * 16 + q16];
                if (sB3 >= 0) vB3 = xf[sB3 * 16 + q16];
                ACCF4(accA, vA0, vA1)
                ACCF4(accA, vA2, vA3)
                ACCF4(accB, vB0, vB1)
                ACCF4(accB, vB2, vB3)
            }
#pragma unroll
            for (int m = 16; m <= 32; m <<= 1)
#pragma unroll
                for (int k = 0; k < 4; k++) {
                    accA[k] += __shfl_xor(accA[k], m, 64);
                    accB[k] += __shfl_xor(accB[k], m, 64);
                }
            float avA = 0.0f, avB = 0.0f;
#pragma unroll
            for (int k = 0; k < 4; k++) {
                float vA = __shfl(accA[k], lane >> 2, 64);
                float vB = __shfl(accB[k], lane >> 2, 64);
                avA = ((lane & 3) == k) ? vA : avA;
                avB = ((lane & 3) == k) ? vB : avB;
            }
            avA *= 1.0f / fmaxf((float)da, 1.0f);
            avB *= 1.0f / fmaxf((float)db, 1.0f);
            aggbuf[(long long)na * 64 + lane] = __float2bfloat16(avA);
            aggbuf[(long long)nb * 64 + lane] = __float2bfloat16(avB);
        }
    }
}

// ---------------- layer-1+2 GEMMs (MFMA, dense coalesced staging) ----------------
// Writes z/r slice-major: zbufT[2][N][16], rbufT[2][N][16] (for node2's L2 slicing).
__global__ __launch_bounds__(256) void gemm1_kernel(
    const void* __restrict__ x, const bf16* __restrict__ aggbuf,
    const void* __restrict__ W1l, const void* __restrict__ b1l,
    const void* __restrict__ W1r, const void* __restrict__ W2l,
    const void* __restrict__ b2l, const void* __restrict__ W2r,
    bf16* __restrict__ zbufT, bf16* __restrict__ rbufT,
    const int* __restrict__ flags) {
    __shared__ __align__(16) unsigned short sW1t[64][136];
    __shared__ __align__(16) unsigned short sA[64][136];
    __shared__ __align__(16) unsigned short sW2t[64][72];
    __shared__ __align__(16) unsigned short sH[64][72];
    __shared__ float sB1[64];
    __shared__ float sB2[32];

    int isbf = flags[0];
    int t = threadIdx.x;
    int n0 = blockIdx.x * 64;

    for (int i = t; i < 64 * 128; i += 256) {
        int n = i & 63, k = i >> 6;
        unsigned short v;
        if (isbf)
            v = (k < 64) ? ((const unsigned short*)W1l)[k * 64 + n]
                         : ((const unsigned short*)W1r)[(k - 64) * 64 + n];
        else
            v = f2bits((k < 64) ? ((const float*)W1l)[k * 64 + n]
                                : ((const float*)W1r)[(k - 64) * 64 + n]);
        sW1t[n][k] = v;
    }
    for (int i = t; i < 64 * 64; i += 256) {
        int n = i & 63, k = i >> 6;
        unsigned short v;
        if (isbf)
            v = (n < 32) ? ((const unsigned short*)W2l)[k * 32 + n]
                         : ((const unsigned short*)W2r)[k * 32 + (n - 32)];
        else
            v = f2bits((n < 32) ? ((const float*)W2l)[k * 32 + n]
                                : ((const float*)W2r)[k * 32 + (n - 32)]);
        sW2t[n][k] = v;
    }
    if (t < 64) sB1[t] = get_f(b1l, t, isbf);
    if (t < 32) sB2[t] = get_f(b2l, t, isbf);

    const uint4* ag4 = (const uint4*)aggbuf;
    if (isbf) {
        const uint4* x4 = (const uint4*)x;
        for (int i = t; i < 64 * 16; i += 256) {
            int m = i >> 4, c = i & 15;
            int nn = min(n0 + m, N_NODES - 1);
            uint4 v = (c < 8) ? ag4[(long long)nn * 8 + c]
                              : x4[(long long)nn * 8 + (c - 8)];
            *(uint4*)&sA[m][c * 8] = v;
        }
    } else {
        for (int i = t; i < 64 * 8; i += 256) {
            int m = i >> 3, c = i & 7;
            int nn = min(n0 + m, N_NODES - 1);
            *(uint4*)&sA[m][c * 8] = ag4[(long long)nn * 8 + c];
        }
        const float* xf = (const float*)x;
        for (int i = t; i < 64 * 64; i += 256) {
            int m = i >> 6, c = i & 63;
            int nn = min(n0 + m, N_NODES - 1);
            sA[m][64 + c] = f2bf_bits(xf[(long long)nn * 64 + c]);
        }
    }
    __syncthreads();

    int w = t >> 6, lane = t & 63;
    int mbase = w * 16;
    int q = lane >> 4, r15 = lane & 15;
    f32x4 acc1[4] = {{0,0,0,0},{0,0,0,0},{0,0,0,0},{0,0,0,0}};
#pragma unroll
    for (int ks = 0; ks < 4; ks++) {
        bf16x8 afrag = *(const bf16x8*)&sA[mbase + r15][ks * 32 + q * 8];
#pragma unroll
        for (int nt = 0; nt < 4; nt++) {
            bf16x8 bfrag = *(const bf16x8*)&sW1t[nt * 16 + r15][ks * 32 + q * 8];
            acc1[nt] = __builtin_amdgcn_mfma_f32_16x16x32_bf16(afrag, bfrag, acc1[nt], 0, 0, 0);
        }
    }
#pragma unroll
    for (int nt = 0; nt < 4; nt++) {
        int col = nt * 16 + r15;
        float bias = sB1[col];
#pragma unroll
        for (int rr = 0; rr < 4; rr++) {
            int m = mbase + q * 4 + rr;
            sH[m][col] = f2bf_bits(fmaxf(acc1[nt][rr] + bias, 0.0f));
        }
    }
    __syncthreads();

    f32x4 acc2[4] = {{0,0,0,0},{0,0,0,0},{0,0,0,0},{0,0,0,0}};
#pragma unroll
    for (int ks = 0; ks < 2; ks++) {
        bf16x8 afrag = *(const bf16x8*)&sH[mbase + r15][ks * 32 + q * 8];
#pragma unroll
        for (int nt = 0; nt < 4; nt++) {
            bf16x8 bfrag = *(const bf16x8*)&sW2t[nt * 16 + r15][ks * 32 + q * 8];
            acc2[nt] = __builtin_amdgcn_mfma_f32_16x16x32_bf16(afrag, bfrag, acc2[nt], 0, 0, 0);
        }
    }
#pragma unroll
    for (int nt = 0; nt < 4; nt++) {
        int col = nt * 16 + r15;
#pragma unroll
        for (int rr = 0; rr < 4; rr++) {
            int m = mbase + q * 4 + rr;
            int n = n0 + m;
            if (n < N_NODES) {
                float v = acc2[nt][rr];
                if (col < 32) {
                    zbufT[(long long)(col >> 4) * (N_NODES * 16) +
                          (long long)n * 16 + (col & 15)] = __float2bfloat16(v);
                } else {
                    int c2 = col - 32;
                    rbufT[(long long)(c2 >> 4) * (N_NODES * 16) +
                          (long long)n * 16 + (c2 & 15)] =
                        __float2bfloat16(v + sB2[c2]);
                }
            }
        }
    }
}

// ---------------- layer-2: gather z (slice-major, shuffle-free, nt-streams)
// 2 slices x 16ch; cz=(bid%8)>>2; reads zT immediately after gemm1 wrote it
// (the proven producer-warm configuration, r2: FETCH 37MB).
__global__ __launch_bounds__(256) void node2_kernel(
    const int* __restrict__ row_start, const int* __restrict__ csr_src,
    const uint* __restrict__ zTu, const bf16* __restrict__ rbufT,
    void* __restrict__ out, const int* __restrict__ flags) {
    int isbf = flags[0];
    int t = threadIdx.x;
    int lane = t & 63;
    int w = t >> 6;
    int bid = blockIdx.x;
    int cz = (bid & 7) >> 2;                                   // slice 0..1
    int wid = ((((bid >> 3) << 2) | (bid & 3)) << 2) + w;      // wave id within cz
    int nw = gridDim.x * 2;                                    // waves per cz
    int g8 = lane & 0x38, c8 = lane & 7;
    int g = lane >> 3;
    const uint* su = zTu + (long long)cz * (N_NODES * 8);
    const uint* ru = (const uint*)(rbufT + (long long)cz * (N_NODES * 16));

    for (int oct = wid; oct < NOCT; oct += nw) {
        int nb0 = oct * 8;
        float a0, a1;
        int dg;
        slice_gather8(su, row_start, csr_src, nb0, g8, c8, lane, a0, a1, dg);
        float inv = 1.0f / fmaxf((float)dg, 1.0f);
        int n = nb0 + g;
        uint rb = __builtin_nontemporal_load(ru + n * 8 + c8);
        float r0 = a0 * inv + lo16f(rb);
        float r1 = a1 * inv + hi16f(rb);
        if (isbf) {
            uint pk = (uint)f2bf_bits(r0) | ((uint)f2bf_bits(r1) << 16);
            __builtin_nontemporal_store(pk, (uint*)out + n * 16 + cz * 8 + c8);
        } else {
            float* of = (float*)out;
            __builtin_nontemporal_store(r0, of + (long long)n * 32 + cz * 16 + 2 * c8);
            __builtin_nontemporal_store(r1, of + (long long)n * 32 + cz * 16 + 2 * c8 + 1);
        }
    }
}

extern "C" void kernel_launch(void* const* d_in, const int* in_sizes, int n_in,
                              void* d_out, int out_size, void* d_ws, size_t ws_size,
                              hipStream_t stream) {
    const void* x = d_in[0];
    const void* ei = d_in[1];  // [2, E]: src = [0,E), dst = [E,2E)
    const void* W1l = d_in[2];
    const void* b1l = d_in[3];
    const void* W1r = d_in[4];
    const void* W2l = d_in[5];
    const void* b2l = d_in[6];
    const void* W2r = d_in[7];

    // workspace layout (~42 MB), triple-aliased across pipeline phases:
    //   [0, 16.0MB)      bucket_data (dead after csrB)  / aggbuf (gather1->gemm1)
    //   [29.2, 42.0MB)   xT (transpose->gather1, bf16)  / zbufT+rbufT (gemm1->node2)
    char* ws = (char*)d_ws;
    uint* bucket_data = (uint*)ws;                    // NBKT*BKT_CAP u32 = 16.0 MB
    bf16* aggbuf = (bf16*)ws;                         // N*64 bf16 = 12.8 MB (alias)
    int* csr_src = (int*)(ws + 16015424);             // E i32 = 12.8 MB
    int* row_start = (int*)(ws + 28815424);           // N+1 i32
    int* bucket_cursor = (int*)(ws + 29215488);       // NBKT i32
    int* bucket_base = (int*)(ws + 29217088);         // NBKT i32
    uint* xtu = (uint*)(ws + 29218688);               // 4*N*16 bf16 = 12.8 MB (alias)
    bf16* zbufT = (bf16*)(ws + 29218688);             // 2*N*16 bf16 = 6.4 MB
    bf16* rbufT = (bf16*)(ws + 35618688);             // 2*N*16 bf16 = 6.4 MB
    int* flags = (int*)(ws + 42018688);               // 2 i32

    hipMemsetAsync(bucket_cursor, 0, NBKT * 4, stream);

    detect_kernel<<<1, 64, 0, stream>>>(x, ei, flags);
    scatterA_kernel<<<NBKT, 256, 0, stream>>>(ei, bucket_cursor, bucket_data, flags);
    scanBuckets_kernel<<<1, 512, 0, stream>>>(bucket_cursor, bucket_base);
    csrB_kernel<<<NBKT, 256, 0, stream>>>(bucket_cursor, bucket_base, bucket_data,
                                          csr_src, row_start);
    // producer-warm pairs: transpose 2 slices, gather them IMMEDIATELY
    transpose2_kernel<<<782, 256, 0, stream>>>(x, (uint4*)xtu, flags, 0);
    gather1_kernel<<<4096, 256, 0, stream>>>(x, xtu, row_start, csr_src, aggbuf,
                                             flags, 0);
    transpose2_kernel<<<782, 256, 0, stream>>>(x, (uint4*)xtu, flags, 2);
    gather1_kernel<<<4096, 256, 0, stream>>>(x, xtu, row_start, csr_src, aggbuf,
                                             flags, 2);
    gemm1_kernel<<<1563, 256, 0, stream>>>(x, aggbuf, W1l, b1l, W1r, W2l, b2l,
                                           W2r, zbufT, rbufT, flags);
    node2_kernel<<<4096, 256, 0, stream>>>(row_start, csr_src, (const uint*)zbufT,
                                           rbufT, d_out, flags);
}